// Round 5
// baseline (128.596 us; speedup 1.0000x reference)
//
#include <hip/hip_runtime.h>
#include <math.h>

#define BDIM 8
#define NDIM 128
#define TDIM 1024
#define TPB 256   // 2 float4-iterations per thread; wave covers 128 contiguous t per iter

#define EPS_F 1e-12f
#define RHO_LIM_F (1.0f - 1e-6f)
#define PI_F 3.14159265358979323846f

// One block per (b1,b2,n) row. Thread tid, iter j handles elements t=2(tid+j*TPB), t+1
// (one float4 of k, one float4 of out — fully lane-coalesced).
// Conv halo comes from adjacent lanes via __shfl (ds_bpermute, no barrier);
// wave-edge lanes (0 and 63) recompute their neighbor element directly
// (predicated on 2/64 lanes, inputs are L1-hot). No LDS, no __syncthreads.

__device__ __forceinline__ void kfun(float kgp, float kntk, float vx, float vy,
                                     float one_m, float coef, bool fast,
                                     float& c0, float& cn)
{
    const float inv2pi = 0.15915494309189535f;
    const float p = sqrtf(fmaxf(vx, 0.0f) * fmaxf(vy, 0.0f));
    const float r = fminf(fmaxf(kgp * __builtin_amdgcn_rcpf(fmaxf(p, EPS_F)), -RHO_LIM_F), RHO_LIM_F);
    if (fast) {
        // exact when one_m == (1-a)^2 == 0: theta/s terms vanish
        const float hc = 0.5f * coef;
        c0 = p * r * hc;
        cn = hc * kntk;
    } else {
        const float th = acosf(r);
        const float s  = sqrtf(1.0f - r * r);
        const float br = coef * PI_F - one_m * th;
        c0 = p * inv2pi * (one_m * s + r * br);
        cn = br * inv2pi * kntk;
    }
}

__global__ __launch_bounds__(TPB) void conv_arccos_kernel(
    const float* __restrict__ k,      // (B,B,N,T,2)
    const float* __restrict__ leak,   // scalar
    const float* __restrict__ alpha,  // (3,)
    const float* __restrict__ beta,   // scalar
    float* __restrict__ out)          // (B,B,N,T,2)
{
    const int row  = blockIdx.x;          // 0 .. B*B*N-1
    const int n    = row % NDIM;
    const int bb   = row / NDIM;
    const int b2   = bb % BDIM;
    const int b1   = bb / BDIM;
    const int tid  = threadIdx.x;
    const int lane = tid & 63;

    // forward value of clamp_pg(x) is max(x, 0)
    const float a   = fmaxf(leak[0], 0.0f);
    const float w0  = fmaxf(alpha[0], 0.0f);
    const float w1  = fmaxf(alpha[1], 0.0f);
    const float w2  = fmaxf(alpha[2], 0.0f);
    const float bia = fmaxf(beta[0], 0.0f);

    const float one_m = (1.0f - a) * (1.0f - a);
    const float coef  = 1.0f + a * a;
    const bool  fast  = (one_m == 0.0f);

    const float4* krow4 = (const float4*)(k + (size_t)row * TDIM * 2);
    const float2* krow2 = (const float2*)(k + (size_t)row * TDIM * 2);
    // v[b, t] = k[b, b, 0, t, 0]
    const float2* vrx = (const float2*)(k) + (size_t)(b1 * BDIM + b1) * NDIM * TDIM;
    const float2* vry = (const float2*)(k) + (size_t)(b2 * BDIM + b2) * NDIM * TDIM;
    float4* orow = (float4*)(out + (size_t)row * TDIM * 2);

    const int lim = TDIM - n;  // vy in-bounds iff t+i < lim

    #pragma unroll
    for (int j = 0; j < TDIM / (2 * TPB); ++j) {
        const int f = tid + j * TPB;   // float4 index
        const int t = 2 * f;

        const float4 kv  = krow4[f];                    // kgp0,kntk0,kgp1,kntk1
        const float4 vx2 = ((const float4*)vrx)[f];     // vx[t] (.x), vx[t+1] (.z)
        const float vy0 = (t     < lim) ? vry[n + t    ].x : 0.0f;
        const float vy1 = (t + 1 < lim) ? vry[n + t + 1].x : 0.0f;

        float c00, cn0, c01, cn1;
        kfun(kv.x, kv.y, vx2.x, vy0, one_m, coef, fast, c00, cn0);
        kfun(kv.z, kv.w, vx2.z, vy1, one_m, coef, fast, c01, cn1);

        // neighbor halos from adjacent lanes (lane l-1 owns t-2,t-1; l+1 owns t+2,t+3)
        float c0l = __shfl_up(c01, 1);
        float cnl = __shfl_up(cn1, 1);
        float c0r = __shfl_down(c00, 1);
        float cnr = __shfl_down(cn0, 1);

        // wave-edge lanes recompute the neighbor element directly
        const bool lo = (lane == 0);
        const bool hi = (lane == 63);
        if (lo || hi) {
            const int e = lo ? (t - 1) : (t + 2);
            float ec0 = 0.0f, ecn = 0.0f;
            if (e >= 0 && e < TDIM) {
                const float2 kp  = krow2[e];
                const float  evx = vrx[e].x;
                const float  evy = (e < lim) ? vry[n + e].x : 0.0f;
                kfun(kp.x, kp.y, evx, evy, one_m, coef, fast, ec0, ecn);
            }
            if (lo) { c0l = ec0; cnl = ecn; }
            else    { c0r = ec0; cnr = ecn; }
        }

        const float kg0 = w0 * c0l + w1 * c00 + w2 * c01;
        const float kg1 = w0 * c00 + w1 * c01 + w2 * c0r;
        const float kn0 = w0 * cnl + w1 * cn0 + w2 * cn1 + kg0;
        const float kn1 = w0 * cn0 + w1 * cn1 + w2 * cnr + kg1;

        float4 o;
        o.x = kg0 + bia;
        o.y = kn0 + bia;
        o.z = kg1 + bia;
        o.w = kn1 + bia;
        orow[f] = o;
    }
}

extern "C" void kernel_launch(void* const* d_in, const int* in_sizes, int n_in,
                              void* d_out, int out_size, void* d_ws, size_t ws_size,
                              hipStream_t stream) {
    const float* k     = (const float*)d_in[0];
    const float* leak  = (const float*)d_in[1];
    const float* alpha = (const float*)d_in[2];
    const float* beta  = (const float*)d_in[3];
    float* out = (float*)d_out;

    const int n_rows = BDIM * BDIM * NDIM;   // 8192
    conv_arccos_kernel<<<n_rows, TPB, 0, stream>>>(k, leak, alpha, beta, out);
}

// Round 6
// 119.787 us; speedup vs baseline: 1.0735x; 1.0735x over previous
//
#include <hip/hip_runtime.h>
#include <math.h>

#define BDIM 8
#define NDIM 128
#define TDIM 1024
#define TPB 512    // one float4 (elements t,t+1) per thread per row
#define ROWS 4     // rows per block; N=128 divisible by 4 -> same (b1,b2) per block
#define LSTRIDE 1028  // per-row LDS stride: idx0 = left halo (t=-1), t at idx t+1, right halo idx TDIM+1

#define EPS_F 1e-12f
#define RHO_LIM_F (1.0f - 1e-6f)
#define PI_F 3.14159265358979323846f

// Fast path identity (exact for all p >= 0 incl. p < eps):
//   p * clamp(kgp / max(p,eps), -RHO, RHO) == clamp(kgp, -p*RHO, p*RHO)
// so when one_m == (1-a)^2 == 0:  c0 = hc * med3(kgp, -p*RHO, p*RHO), no rcp.

__device__ __forceinline__ void kfun(float kgp, float kntk, float vx, float vy,
                                     float one_m, float coef, bool fast,
                                     float& c0, float& cn)
{
    const float inv2pi = 0.15915494309189535f;
    const float p = sqrtf(fmaxf(vx, 0.0f) * fmaxf(vy, 0.0f));
    if (fast) {
        const float hc = 0.5f * coef;
        const float pr = p * RHO_LIM_F;
        c0 = hc * fminf(fmaxf(kgp, -pr), pr);   // v_med3_f32
        cn = hc * kntk;
    } else {
        const float r  = fminf(fmaxf(kgp * __builtin_amdgcn_rcpf(fmaxf(p, EPS_F)), -RHO_LIM_F), RHO_LIM_F);
        const float th = acosf(r);
        const float s  = sqrtf(1.0f - r * r);
        const float br = coef * PI_F - one_m * th;
        c0 = p * inv2pi * (one_m * s + r * br);
        cn = br * inv2pi * kntk;
    }
}

__global__ __launch_bounds__(TPB) void conv_arccos_kernel(
    const float* __restrict__ k,      // (B,B,N,T,2)
    const float* __restrict__ leak,   // scalar
    const float* __restrict__ alpha,  // (3,)
    const float* __restrict__ beta,   // scalar
    float* __restrict__ out)          // (B,B,N,T,2)
{
    __shared__ float sc0[ROWS * LSTRIDE];
    __shared__ float scn[ROWS * LSTRIDE];

    const int base = blockIdx.x * ROWS;   // first row of this block
    const int n0   = base % NDIM;         // n of first row (multiple of 4)
    const int bb   = base / NDIM;
    const int b2   = bb % BDIM;
    const int b1   = bb / BDIM;
    const int tid  = threadIdx.x;
    const int t    = tid * 2;

    // forward value of clamp_pg(x) is max(x, 0)
    const float a   = fmaxf(leak[0], 0.0f);
    const float w0  = fmaxf(alpha[0], 0.0f);
    const float w1  = fmaxf(alpha[1], 0.0f);
    const float w2  = fmaxf(alpha[2], 0.0f);
    const float bia = fmaxf(beta[0], 0.0f);

    const float one_m = (1.0f - a) * (1.0f - a);
    const float coef  = 1.0f + a * a;
    const bool  fast  = (one_m == 0.0f);

    // v[b, t] = k[b, b, 0, t, 0]
    const float2* vrx = (const float2*)(k) + (size_t)(b1 * BDIM + b1) * NDIM * TDIM;
    const float2* vry = (const float2*)(k) + (size_t)(b2 * BDIM + b2) * NDIM * TDIM;

    // zero halos (left idx 0, right idx TDIM+1, per row)
    if (tid < ROWS * 2) {
        const int r   = tid >> 1;
        const int idx = r * LSTRIDE + ((tid & 1) ? (TDIM + 1) : 0);
        sc0[idx] = 0.0f;
        scn[idx] = 0.0f;
    }

    // ---- gather shared inputs ----
    // vx[t], vx[t+1] shared by all 4 rows (16B coalesced)
    const float4 vx2 = ((const float4*)vrx)[tid];
    // vy values y_j = v[b2, n0+t+j], j=0..4 cover row rl elem i at j=rl+i.
    // (n0+t) is even -> 16B-aligned float4 loads over the float2 array; lanes
    // stride 16B -> fully coalesced. Reads past row 0 of the (b2,b2) slice are
    // in-bounds garbage, masked below.
    const float4* vyp = (const float4*)(vry + (n0 + t));
    const float4 vyA = vyp[0];            // .x = y0, .z = y1
    const float4 vyB = vyp[1];            // .x = y2, .z = y3
    float y0 = vyA.x, y1 = vyA.z, y2 = vyB.x, y3 = vyB.z;
    float y4 = vry[n0 + t + 4].x;         // L1-hot (neighbors' vyA/vyB lines)
    const int ty = n0 + t;
    if (ty     >= TDIM) y0 = 0.0f;
    if (ty + 1 >= TDIM) y1 = 0.0f;
    if (ty + 2 >= TDIM) y2 = 0.0f;
    if (ty + 3 >= TDIM) y3 = 0.0f;
    if (ty + 4 >= TDIM) y4 = 0.0f;
    const float yv[6] = { y0, y1, y2, y3, y4, 0.0f };

    // ---- phase 1: 4 rows, one float4 of k each ----
    #pragma unroll
    for (int rl = 0; rl < ROWS; ++rl) {
        const float4 kv = ((const float4*)(k + (size_t)(base + rl) * TDIM * 2))[tid];
        float c00, cn0, c01, cn1;
        kfun(kv.x, kv.y, vx2.x, yv[rl],     one_m, coef, fast, c00, cn0);
        kfun(kv.z, kv.w, vx2.z, yv[rl + 1], one_m, coef, fast, c01, cn1);
        const int bi = rl * LSTRIDE + t + 1;
        sc0[bi]     = c00;
        sc0[bi + 1] = c01;
        scn[bi]     = cn0;
        scn[bi + 1] = cn1;
    }

    __syncthreads();

    // ---- phase 2: 3-tap conv per row, bias folded into FMA seed ----
    #pragma unroll
    for (int rl = 0; rl < ROWS; ++rl) {
        const int bi = rl * LSTRIDE + t;
        const float c0l = sc0[bi], c00 = sc0[bi + 1], c01 = sc0[bi + 2], c0r = sc0[bi + 3];
        const float cnl = scn[bi], cn0 = scn[bi + 1], cn1 = scn[bi + 2], cnr = scn[bi + 3];

        // kg = conv(c0) + bia ; kn = conv(cn) + kg   (kn = conv(cn)+conv(c0)+bia)
        const float kg0 = fmaf(w0, c0l, fmaf(w1, c00, fmaf(w2, c01, bia)));
        const float kg1 = fmaf(w0, c00, fmaf(w1, c01, fmaf(w2, c0r, bia)));
        const float kn0 = fmaf(w0, cnl, fmaf(w1, cn0, fmaf(w2, cn1, kg0)));
        const float kn1 = fmaf(w0, cn0, fmaf(w1, cn1, fmaf(w2, cnr, kg1)));

        float4 o;
        o.x = kg0; o.y = kn0; o.z = kg1; o.w = kn1;
        ((float4*)(out + (size_t)(base + rl) * TDIM * 2))[tid] = o;
    }
}

extern "C" void kernel_launch(void* const* d_in, const int* in_sizes, int n_in,
                              void* d_out, int out_size, void* d_ws, size_t ws_size,
                              hipStream_t stream) {
    const float* k     = (const float*)d_in[0];
    const float* leak  = (const float*)d_in[1];
    const float* alpha = (const float*)d_in[2];
    const float* beta  = (const float*)d_in[3];
    float* out = (float*)d_out;

    const int n_blocks = BDIM * BDIM * NDIM / ROWS;   // 2048
    conv_arccos_kernel<<<n_blocks, TPB, 0, stream>>>(k, leak, alpha, beta, out);
}